// Round 8
// baseline (114.727 us; speedup 1.0000x reference)
//
#include <hip/hip_runtime.h>

typedef _Float16 f16;
typedef f16 f16x4 __attribute__((ext_vector_type(4)));
typedef f16 f16x8 __attribute__((ext_vector_type(8)));
typedef float f32x4 __attribute__((ext_vector_type(4)));
typedef float f32x16 __attribute__((ext_vector_type(16)));

#define FIN  64
#define FOUT 64
#define HI   128
#define WI   128
#define HO   126
#define WO   126
#define HIWI (HI*WI)
#define NPH  16      // phases (4 input channels each)
#define CPH  4

// ws layout: weight-fragment table f16 [i][ob][lane][8] = 128 KiB (the B
// operand); Wc f32 table [i][o] = 16 KiB at byte offset 131072.
// k-labeling (validated end-to-end in round 6; symmetric between operands):
//   k = g*4 + (j&3) + 8*(j>>2),  g = lane>>5, j = 0..7
//   taps k=4*dy+dx (dx<3 real, dx=3 zero), k12 = bias slot (pixel side = 1)

__global__ __launch_bounds__(256) void prepass(
    const float* __restrict__ Wf, const float* __restrict__ bf,
    const float* __restrict__ Wc, unsigned short* __restrict__ ws)
{
    int t = blockIdx.x * 256 + threadIdx.x;
    if (t < 8192) {                      // entries: t = (i*2+ob)*64 + l
        int i  = t >> 7;
        int ob = (t >> 6) & 1;
        int l  = t & 63;
        int g  = l >> 5, n = l & 31;
        int o  = ob * 32 + n;
        unsigned short h[8];
#pragma unroll
        for (int j = 0; j < 8; ++j) {
            int k = g * 4 + (j & 3) + 8 * (j >> 2);
            float v = 0.0f;
            if (k < 12) {
                int dy = k >> 2, dx = k & 3;
                if (dx < 3) v = Wf[((size_t)o * FIN + i) * 9 + dy * 3 + dx];
            } else if (k == 12) {
                v = bf[o * FIN + i];
            }
            f16 hv = (f16)v;
            h[j] = *(unsigned short*)&hv;
        }
        uint4 pk;
        pk.x = h[0] | ((unsigned)h[1] << 16);
        pk.y = h[2] | ((unsigned)h[3] << 16);
        pk.z = h[4] | ((unsigned)h[5] << 16);
        pk.w = h[6] | ((unsigned)h[7] << 16);
        *(uint4*)&ws[(size_t)t * 8] = pk;
    } else if (t < 8192 + 4096) {        // Wc f32 table: [i][o] = Wc[o][i]
        int t2 = t - 8192;
        int i = t2 >> 6, o = t2 & 63;
        float* wcf = (float*)(ws + 65536);
        wcf[t2] = Wc[o * FIN + i];
    }
}

__global__ __launch_bounds__(256, 4) void conv_mfma(
    const float* __restrict__ x, const float* __restrict__ bc,
    const unsigned short* __restrict__ ws, float* __restrict__ out)
{
    // x tiles: 4 channels x 18 halo rows x 9 col-slots (f16x4 window quads), x2 buf
    __shared__ f16x4 xsl[2][CPH * 18 * 9];   // 10.1 KB
    __shared__ float wcl[32][68];            // 8.5 KB  [oo][i], +4 pad vs bank stride

    const int tid = threadIdx.x;
    const int l   = tid & 63, w = tid >> 6;
    const int g   = l >> 5;
    const int m   = l & 31;              // A-row (pixel) for loads; C-col (o) for output
    const int wy  = w >> 1, wx = w & 1;
    const int prow = wy * 8 + (m >> 2);  // this lane's A-operand pixel
    const int sx   = wx * 4 + (m & 3);
    const int rx   = blockIdx.x >> 1;
    const int oh   = blockIdx.x & 1;     // o-half (0: o<32, 1: o>=32)
    const int row0 = rx * 16;
    const int col0 = blockIdx.y * 8;
    const int b    = blockIdx.z;
    const int o_lane = oh * 32 + m;

    // ---- stage Wc transposed to [oo][i] (2048 entries, once) ----
    {
        const float* wcf = (const float*)(ws + 65536);
#pragma unroll
        for (int k2 = 0; k2 < 8; ++k2) {
            int idx = tid + k2 * 256;
            int oo = idx >> 6, i = idx & 63;
            wcl[oo][i] = wcf[i * 64 + oh * 32 + oo];
        }
    }

    // ---- x staging units: 576 (slot,ch) units/phase, <=3 per thread ----
    const float* xb = x + (size_t)b * FIN * HIWI;
    int ug[3][4]; int ub[3]; int ulds[3]; bool uv[3];
#pragma unroll
    for (int u = 0; u < 3; ++u) {
        int unit = tid + u * 256;
        uv[u] = (unit < 576);
        int ch = uv[u] ? (unit / 144) : 0;
        int slot = uv[u] ? (unit - ch * 144) : 0;
        int r = slot >> 3, s = slot & 7;
        int gy = min(row0 + r, HI - 1);
#pragma unroll
        for (int c = 0; c < 4; ++c)
            ug[u][c] = gy * WI + min(col0 + s + c, WI - 1);
        ub[u]   = ch;
        ulds[u] = (ch * 18 + r) * 9 + s;
    }

    // prologue: stage phase 0 into buffer 0
#pragma unroll
    for (int u = 0; u < 3; ++u) if (uv[u]) {
        const float* xp = xb + (size_t)ub[u] * HIWI;
        f16x4 pk;
        pk[0] = (f16)xp[ug[u][0]]; pk[1] = (f16)xp[ug[u][1]];
        pk[2] = (f16)xp[ug[u][2]]; pk[3] = (f16)xp[ug[u][3]];
        xsl[0][ulds[u]] = pk;
    }

    // B-fragment (weights) prefetch for phase 0
    const uint4* Btab = (const uint4*)ws;
    uint4 Bc[CPH], Bn[CPH];
#pragma unroll
    for (int ch = 0; ch < CPH; ++ch)
        Bc[ch] = Btab[(size_t)(ch * 2 + oh) * 64 + l];

    f32x16 acc = {}, zero = {};
    const f16x4 ONEV = {(f16)1.0f, (f16)0.0f, (f16)0.0f, (f16)0.0f};

    for (int ph = 0; ph < NPH; ++ph) {
        const int cur = ph & 1;
        const bool more = (ph + 1 < NPH);

        // issue next-phase loads early (consumed after the compute block)
        float sv[3][4];
        if (more) {
            const int ib = (ph + 1) * CPH;
#pragma unroll
            for (int u = 0; u < 3; ++u) if (uv[u]) {
                const float* xp = xb + (size_t)(ib + ub[u]) * HIWI;
#pragma unroll
                for (int c = 0; c < 4; ++c) sv[u][c] = xp[ug[u][c]];
            }
#pragma unroll
            for (int ch = 0; ch < CPH; ++ch)
                Bn[ch] = Btab[(size_t)((ib + ch) * 2 + oh) * 64 + l];
        }

        __syncthreads();   // buf[cur] writes from previous phase visible

        // one ds_read_b128 covers Wc for this lane's o across all 4 channels
        const f32x4 wcq = *(const f32x4*)&wcl[m][ph * CPH];

#pragma unroll
        for (int ch = 0; ch < CPH; ++ch) {
            const int rb = ch * 18;
            f16x4 A1  = xsl[cur][(rb + prow + g) * 9 + sx];
            f16x4 A2r = xsl[cur][(rb + prow + 2) * 9 + sx];
            f16x4 A2  = g ? ONEV : A2r;          // g=1 upper half = bias slot
            f16x8 Af;
#pragma unroll
            for (int c = 0; c < 4; ++c) { Af[c] = A1[c]; Af[4 + c] = A2[c]; }
            f16x8 Bf = *(f16x8*)&Bc[ch];
            f32x16 S = __builtin_amdgcn_mfma_f32_32x32x16_f16(Af, Bf, zero, 0, 0, 0);
            const float wcv = wcq[ch];
#pragma unroll
            for (int r = 0; r < 16; ++r)
                acc[r] = fmaf(wcv, fmaxf(S[r], 0.0f), acc[r]);
        }

        // commit staged channels into the other buffer; rotate B-frags
        if (more) {
#pragma unroll
            for (int u = 0; u < 3; ++u) if (uv[u]) {
                f16x4 pk;
                pk[0] = (f16)sv[u][0]; pk[1] = (f16)sv[u][1];
                pk[2] = (f16)sv[u][2]; pk[3] = (f16)sv[u][3];
                xsl[cur ^ 1][ulds[u]] = pk;
            }
#pragma unroll
            for (int ch = 0; ch < CPH; ++ch) Bc[ch] = Bn[ch];
        }
    }

    // ---- epilogue: lane owns o_lane; reg r holds pixel m_r=(r&3)+8*(r>>2)+4g ----
    const float bcv = bc[o_lane];
    const int horow = row0 + wy * 8;
    const int wob   = col0 + wx * 4;
    const size_t plane = (size_t)(b * FOUT + o_lane) * (HO * WO);
#pragma unroll
    for (int r = 0; r < 16; ++r) {
        int ho = horow + 2 * (r >> 2) + g;
        int wo = wob + (r & 3);
        if (ho < HO && wo < WO)
            out[plane + (size_t)ho * WO + wo] = acc[r] + bcv;
    }
}

extern "C" void kernel_launch(void* const* d_in, const int* in_sizes, int n_in,
                              void* d_out, int out_size, void* d_ws, size_t ws_size,
                              hipStream_t stream) {
    const float* x  = (const float*)d_in[0];
    const float* Wf = (const float*)d_in[1];
    const float* bf = (const float*)d_in[2];
    const float* Wc = (const float*)d_in[3];
    const float* bc = (const float*)d_in[4];
    float* out = (float*)d_out;
    unsigned short* ws = (unsigned short*)d_ws;

    hipLaunchKernelGGL(prepass, dim3(48), dim3(256), 0, stream, Wf, bf, Wc, ws);

    // x: 8 row-tiles x 2 o-halves; y: 16 col-tiles; z: 4 batches = 1024 blocks
    dim3 grid(16, 16, 4);
    hipLaunchKernelGGL(conv_mfma, grid, dim3(256), 0, stream, x, bc, ws, out);
}

// Round 9
// 106.633 us; speedup vs baseline: 1.0759x; 1.0759x over previous
//
#include <hip/hip_runtime.h>

typedef _Float16 f16;
typedef f16 f16x4 __attribute__((ext_vector_type(4)));
typedef f16 f16x8 __attribute__((ext_vector_type(8)));
typedef float f32x4 __attribute__((ext_vector_type(4)));
typedef float f32x16 __attribute__((ext_vector_type(16)));

#define FIN  64
#define FOUT 64
#define HI   128
#define WI   128
#define HO   126
#define WO   126
#define HIWI (HI*WI)
#define NPH  16      // phases (4 input channels each)
#define CPH  4

// ws layout: weight-fragment table f16 [i][ob][lane][8] = 128 KiB (B operand);
// Wc f32 table [i][o] = 16 KiB at byte offset 131072.
// k-labeling (validated end-to-end in rounds 6/8; symmetric between operands):
//   k = g*4 + (j&3) + 8*(j>>2),  g = lane>>5, j = 0..7
//   taps k=4*dy+dx (dx<3 real, dx=3 zero), k12 = bias slot (pixel side = 1)

__global__ __launch_bounds__(256) void prepass(
    const float* __restrict__ Wf, const float* __restrict__ bf,
    const float* __restrict__ Wc, unsigned short* __restrict__ ws)
{
    int t = blockIdx.x * 256 + threadIdx.x;
    if (t < 8192) {                      // entries: t = (i*2+ob)*64 + l
        int i  = t >> 7;
        int ob = (t >> 6) & 1;
        int l  = t & 63;
        int g  = l >> 5, n = l & 31;
        int o  = ob * 32 + n;
        unsigned short h[8];
#pragma unroll
        for (int j = 0; j < 8; ++j) {
            int k = g * 4 + (j & 3) + 8 * (j >> 2);
            float v = 0.0f;
            if (k < 12) {
                int dy = k >> 2, dx = k & 3;
                if (dx < 3) v = Wf[((size_t)o * FIN + i) * 9 + dy * 3 + dx];
            } else if (k == 12) {
                v = bf[o * FIN + i];
            }
            f16 hv = (f16)v;
            h[j] = *(unsigned short*)&hv;
        }
        uint4 pk;
        pk.x = h[0] | ((unsigned)h[1] << 16);
        pk.y = h[2] | ((unsigned)h[3] << 16);
        pk.z = h[4] | ((unsigned)h[5] << 16);
        pk.w = h[6] | ((unsigned)h[7] << 16);
        *(uint4*)&ws[(size_t)t * 8] = pk;
    } else if (t < 8192 + 4096) {        // Wc f32 table: [i][o] = Wc[o][i]
        int t2 = t - 8192;
        int i = t2 >> 6, o = t2 & 63;
        float* wcf = (float*)(ws + 65536);
        wcf[t2] = Wc[o * FIN + i];
    }
}

__global__ __launch_bounds__(256, 4) void conv_mfma(
    const float* __restrict__ x, const float* __restrict__ bc,
    const unsigned short* __restrict__ ws, float* __restrict__ out)
{
    // x tiles: 4 channels x 18 halo rows x 9 col-slots (f16x4 window quads), x2 buf
    __shared__ f16x4 xsl[2][CPH * 18 * 9];   // 10.1 KB
    __shared__ float wcl[32][68];            // 8.5 KB  [oo][i]
    __shared__ float ot[32][132];            // 16.9 KB transpose buffer [oo][px]

    const int tid = threadIdx.x;
    const int l   = tid & 63, w = tid >> 6;
    const int g   = l >> 5;
    const int m   = l & 31;              // A-row (pixel) for loads; C-col (o) for output
    const int wy  = w >> 1, wx = w & 1;
    const int prow = wy * 8 + (m >> 2);  // this lane's A-operand pixel
    const int sx   = wx * 4 + (m & 3);
    const int rx   = blockIdx.x >> 1;
    const int oh   = blockIdx.x & 1;     // o-half (0: o<32, 1: o>=32)
    const int row0 = rx * 16;
    const int col0 = blockIdx.y * 8;
    const int b    = blockIdx.z;
    const int o_lane = oh * 32 + m;

    // ---- stage Wc transposed to [oo][i] (2048 entries, once) ----
    {
        const float* wcf = (const float*)(ws + 65536);
#pragma unroll
        for (int k2 = 0; k2 < 8; ++k2) {
            int idx = tid + k2 * 256;
            int oo = idx >> 6, i = idx & 63;
            wcl[oo][i] = wcf[i * 64 + oh * 32 + oo];
        }
    }

    // ---- x staging units: 576 (slot,ch) units/phase, <=3 per thread ----
    const float* xb = x + (size_t)b * FIN * HIWI;
    int ug[3][4]; int ub[3]; int ulds[3]; bool uv[3];
#pragma unroll
    for (int u = 0; u < 3; ++u) {
        int unit = tid + u * 256;
        uv[u] = (unit < 576);
        int ch = uv[u] ? (unit / 144) : 0;
        int slot = uv[u] ? (unit - ch * 144) : 0;
        int r = slot >> 3, s = slot & 7;
        int gy = min(row0 + r, HI - 1);
#pragma unroll
        for (int c = 0; c < 4; ++c)
            ug[u][c] = gy * WI + min(col0 + s + c, WI - 1);
        ub[u]   = ch;
        ulds[u] = (ch * 18 + r) * 9 + s;
    }

    // prologue: stage phase 0 into buffer 0
#pragma unroll
    for (int u = 0; u < 3; ++u) if (uv[u]) {
        const float* xp = xb + (size_t)ub[u] * HIWI;
        f16x4 pk;
        pk[0] = (f16)xp[ug[u][0]]; pk[1] = (f16)xp[ug[u][1]];
        pk[2] = (f16)xp[ug[u][2]]; pk[3] = (f16)xp[ug[u][3]];
        xsl[0][ulds[u]] = pk;
    }

    // B-fragment (weights) prefetch for phase 0
    const uint4* Btab = (const uint4*)ws;
    uint4 Bc[CPH], Bn[CPH];
#pragma unroll
    for (int ch = 0; ch < CPH; ++ch)
        Bc[ch] = Btab[(size_t)(ch * 2 + oh) * 64 + l];

    f32x16 acc = {}, zero = {};
    const f16x4 ONEV = {(f16)1.0f, (f16)0.0f, (f16)0.0f, (f16)0.0f};

    for (int ph = 0; ph < NPH; ++ph) {
        const int cur = ph & 1;
        const bool more = (ph + 1 < NPH);

        // issue next-phase loads early (consumed after the compute block)
        float sv[3][4];
        if (more) {
            const int ib = (ph + 1) * CPH;
#pragma unroll
            for (int u = 0; u < 3; ++u) if (uv[u]) {
                const float* xp = xb + (size_t)(ib + ub[u]) * HIWI;
#pragma unroll
                for (int c = 0; c < 4; ++c) sv[u][c] = xp[ug[u][c]];
            }
#pragma unroll
            for (int ch = 0; ch < CPH; ++ch)
                Bn[ch] = Btab[(size_t)((ib + ch) * 2 + oh) * 64 + l];
        }

        __syncthreads();   // buf[cur] writes from previous phase visible

        // one ds_read_b128 covers Wc for this lane's o across all 4 channels
        const f32x4 wcq = *(const f32x4*)&wcl[m][ph * CPH];

#pragma unroll
        for (int ch = 0; ch < CPH; ++ch) {
            const int rb = ch * 18;
            f16x4 A1  = xsl[cur][(rb + prow + g) * 9 + sx];
            f16x4 A2r = xsl[cur][(rb + prow + 2) * 9 + sx];
            f16x4 A2  = g ? ONEV : A2r;          // g=1 upper half = bias slot
            f16x8 Af;
#pragma unroll
            for (int c = 0; c < 4; ++c) { Af[c] = A1[c]; Af[4 + c] = A2[c]; }
            f16x8 Bf = *(f16x8*)&Bc[ch];
            f32x16 S = __builtin_amdgcn_mfma_f32_32x32x16_f16(Af, Bf, zero, 0, 0, 0);
            const float wcv = wcq[ch];
#pragma unroll
            for (int r = 0; r < 16; ++r)
                acc[r] = fmaf(wcv, fmaxf(S[r], 0.0f), acc[r]);
        }

        // commit staged channels into the other buffer; rotate B-frags
        if (more) {
#pragma unroll
            for (int u = 0; u < 3; ++u) if (uv[u]) {
                f16x4 pk;
                pk[0] = (f16)sv[u][0]; pk[1] = (f16)sv[u][1];
                pk[2] = (f16)sv[u][2]; pk[3] = (f16)sv[u][3];
                xsl[cur ^ 1][ulds[u]] = pk;
            }
#pragma unroll
            for (int ch = 0; ch < CPH; ++ch) Bc[ch] = Bn[ch];
        }
    }

    // ---- epilogue: LDS transpose [o][px] then coalesced row stores ----
    const float bcv = bc[o_lane];
#pragma unroll
    for (int r = 0; r < 16; ++r) {
        int mr = (r & 3) + 8 * (r >> 2) + 4 * g;            // wave-local pixel
        int px = (wy * 8 + (mr >> 2)) * 8 + wx * 4 + (mr & 3);
        ot[m][px] = acc[r] + bcv;
    }
    __syncthreads();

    {
        const int oo  = tid >> 3;          // 0..31
        const int seg = tid & 7;           // 2 rows each
        const int o   = oh * 32 + oo;
        const size_t plane = ((size_t)b * FOUT + o) * (size_t)(HO * WO);
#pragma unroll
        for (int rr = 0; rr < 2; ++rr) {
            int trow = 2 * seg + rr;
            int ho = row0 + trow;
            if (ho < HO) {
                const float* src = &ot[oo][trow * 8];
                size_t base = plane + (size_t)ho * WO + col0;
                if (col0 + 8 <= WO) {
#pragma unroll
                    for (int c = 0; c < 8; ++c) out[base + c] = src[c];
                } else {
#pragma unroll
                    for (int c = 0; c < 6; ++c) out[base + c] = src[c];
                }
            }
        }
    }
}

extern "C" void kernel_launch(void* const* d_in, const int* in_sizes, int n_in,
                              void* d_out, int out_size, void* d_ws, size_t ws_size,
                              hipStream_t stream) {
    const float* x  = (const float*)d_in[0];
    const float* Wf = (const float*)d_in[1];
    const float* bf = (const float*)d_in[2];
    const float* Wc = (const float*)d_in[3];
    const float* bc = (const float*)d_in[4];
    float* out = (float*)d_out;
    unsigned short* ws = (unsigned short*)d_ws;

    hipLaunchKernelGGL(prepass, dim3(48), dim3(256), 0, stream, Wf, bf, Wc, ws);

    // x: 8 row-tiles x 2 o-halves; y: 16 col-tiles; z: 4 batches = 1024 blocks
    dim3 grid(16, 16, 4);
    hipLaunchKernelGGL(conv_mfma, grid, dim3(256), 0, stream, x, bc, ws, out);
}

// Round 10
// 48.367 us; speedup vs baseline: 2.3720x; 2.2047x over previous
//
#include <hip/hip_runtime.h>

typedef _Float16 f16;
typedef f16 f16x4 __attribute__((ext_vector_type(4)));
typedef f16 f16x8 __attribute__((ext_vector_type(8)));
typedef float f32x4 __attribute__((ext_vector_type(4)));
typedef float f32x16 __attribute__((ext_vector_type(16)));
typedef unsigned int uint32;

#define FIN  64
#define FOUT 64
#define HI   128
#define WI   128
#define HO   126
#define WO   126
#define HIWI (HI*WI)
#define NPH  16      // phases, 4 input channels each
#define CPH  4
#define TR   8       // tile rows
#define TC   16      // tile cols
#define SR   10      // staged rows (TR+2)
#define SDW  12      // dwords per staged row (10 used, 2 pad -> bank spread)
#define NUNIT (CPH*SR*5)   // 200 float4 staging units per phase

// ws: weight B-fragment table f16 [i][ob][lane][8] = 128 KiB.
// k-labeling (validated end-to-end rounds 6/8/9, symmetric between operands):
//   k = g*4 + (j&3) + 8*(j>>2), g = lane>>5;  taps k=4*dy+dx (dx<3 real,
//   dx=3 zero-weight), k12 = bias slot (pixel operand supplies 1.0).

__global__ __launch_bounds__(256) void prepass(
    const float* __restrict__ Wf, const float* __restrict__ bf,
    unsigned short* __restrict__ ws)
{
    int t = blockIdx.x * 256 + threadIdx.x;   // 0..8191
    int i  = t >> 7;
    int ob = (t >> 6) & 1;
    int l  = t & 63;
    int g  = l >> 5, n = l & 31;
    int o  = ob * 32 + n;
    unsigned short h[8];
#pragma unroll
    for (int j = 0; j < 8; ++j) {
        int k = g * 4 + (j & 3) + 8 * (j >> 2);
        float v = 0.0f;
        if (k < 12) {
            int dy = k >> 2, dx = k & 3;
            if (dx < 3) v = Wf[((size_t)o * FIN + i) * 9 + dy * 3 + dx];
        } else if (k == 12) {
            v = bf[o * FIN + i];
        }
        f16 hv = (f16)v;
        h[j] = *(unsigned short*)&hv;
    }
    uint4 pk;
    pk.x = h[0] | ((uint32)h[1] << 16);
    pk.y = h[2] | ((uint32)h[3] << 16);
    pk.z = h[4] | ((uint32)h[5] << 16);
    pk.w = h[6] | ((uint32)h[7] << 16);
    *(uint4*)&ws[(size_t)t * 8] = pk;
}

__global__ __launch_bounds__(256, 4) void conv_mfma(
    const float* __restrict__ x,  const float* __restrict__ Wc,
    const float* __restrict__ bc, const unsigned short* __restrict__ ws,
    float* __restrict__ out)
{
    __shared__ __align__(16) union {
        struct { uint32 xsl[2][CPH * SR * SDW]; float wcl[32][68]; } a;  // 12.5 KB
        float ot[32][132];                                               // 16.9 KB
    } sm;

    const int tid = threadIdx.x;
    const int l   = tid & 63, w = tid >> 6;
    const int g   = l >> 5;
    const int m   = l & 31;            // A-row (pixel) on loads; C-col (o) on output
    const int prow = m >> 2;           // 0..7 tile row of this lane's pixel
    const int sx   = w * 4 + (m & 3);  // 0..15 tile col

    // XCD-group swizzle: all 16 blocks sharing (rx,b) -> same fid%8 (same XCD)
    const int fid    = blockIdx.x;
    const int grp    = (fid >> 7) * 8 + (fid & 7);   // 0..63 = rx + 16*b
    const int member = (fid >> 3) & 15;              // cy + 8*oh
    const int rx = grp & 15, b = grp >> 4;
    const int cy = member & 7, oh = member >> 3;
    const int row0 = rx * TR;
    const int col0 = cy * TC;
    const int o_lane = oh * 32 + m;

    // ---- stage Wc [oo][i] (coalesced: Wc input is already [o][i]) ----
#pragma unroll
    for (int k = 0; k < 8; ++k) {
        int idx = tid + k * 256;                      // 0..2047
        sm.a.wcl[idx >> 6][idx & 63] =
            Wc[(size_t)(oh * 32 + (idx >> 6)) * FIN + (idx & 63)];
    }

    // ---- staging map: 200 units, one aligned float4 each ----
    const float* xb = x + (size_t)b * FIN * HIWI;
    const bool stg = (tid < NUNIT);
    int uch = 0, goff = 0, widx = 0;
    if (stg) {
        uch = tid / 50;
        int rem = tid % 50;
        int r = rem / 5, u = rem % 5;
        int gy = min(row0 + r, HI - 1);        // clamped rows feed discarded outputs
        int gx = min(col0 + 4 * u, WI - 4);    // clamped cols feed discarded outputs
        goff = gy * WI + gx;
        widx = (uch * SR + r) * SDW + 2 * u;   // even -> 8B-aligned uint2 write
    }

    // prologue: stage channels 0..3 into buffer 0
    if (stg) {
        f32x4 v = *(const f32x4*)&xb[(size_t)uch * HIWI + goff];
        f16x4 h; h[0] = (f16)v[0]; h[1] = (f16)v[1]; h[2] = (f16)v[2]; h[3] = (f16)v[3];
        *(uint2*)&sm.a.xsl[0][widx] = *(uint2*)&h;
    }

    // B-fragment (weights) prefetch for phase 0
    const uint4* Btab = (const uint4*)ws;
    uint4 Bc[CPH], Bn[CPH];
#pragma unroll
    for (int ch = 0; ch < CPH; ++ch)
        Bc[ch] = Btab[(size_t)(ch * 2 + oh) * 64 + l];

    f32x16 acc = {}, zero = {};
    const bool odd = (sx & 1);
    const int  qd  = sx >> 1;

    for (int ph = 0; ph < NPH; ++ph) {
        const int cur = ph & 1;
        const bool more = (ph + 1 < NPH);

        // issue next-phase loads early (consumed after compute)
        f32x4 sv = {};
        if (more) {
            const int ib = (ph + 1) * CPH;
            if (stg) sv = *(const f32x4*)&xb[(size_t)(ib + uch) * HIWI + goff];
#pragma unroll
            for (int ch = 0; ch < CPH; ++ch)
                Bn[ch] = Btab[(size_t)((ib + ch) * 2 + oh) * 64 + l];
        }

        __syncthreads();   // buf[cur] writes from previous phase visible

        const f32x4 wcq = *(const f32x4*)&sm.a.wcl[m][ph * CPH];

#pragma unroll
        for (int ch = 0; ch < CPH; ++ch) {
            const uint32* rp1 = &sm.a.xsl[cur][(ch * SR + prow + g) * SDW];
            const uint32* rp2 = &sm.a.xsl[cur][(ch * SR + prow + 2) * SDW];
            uint32 d0 = rp1[qd], d1 = rp1[qd + 1];        // ds_read2_b32
            uint32 e0 = rp2[qd], e1 = rp2[qd + 1];
            // window quad cols [sx..sx+2] (+don't-care, dx=3 weight is 0)
            uint32 a0 = odd ? ((d0 >> 16) | (d1 << 16)) : d0;
            uint32 a1 = odd ? (d1 >> 16) : d1;
            uint32 b0 = odd ? ((e0 >> 16) | (e1 << 16)) : e0;
            uint32 b1 = odd ? (e1 >> 16) : e1;
            if (g) { b0 = 0x00003c00u; b1 = 0u; }          // bias slot: 1.0h
            uint4 auv = {a0, a1, b0, b1};
            f16x8 Af = *(f16x8*)&auv;
            f16x8 Bf = *(f16x8*)&Bc[ch];
            f32x16 S = __builtin_amdgcn_mfma_f32_32x32x16_f16(Af, Bf, zero, 0, 0, 0);
            const float wcv = wcq[ch];
#pragma unroll
            for (int r = 0; r < 16; ++r)
                acc[r] = fmaf(wcv, fmaxf(S[r], 0.0f), acc[r]);
        }

        // commit staged channels into the other buffer; rotate B-frags
        if (more) {
            if (stg) {
                f16x4 h; h[0] = (f16)sv[0]; h[1] = (f16)sv[1];
                h[2] = (f16)sv[2]; h[3] = (f16)sv[3];
                *(uint2*)&sm.a.xsl[cur ^ 1][widx] = *(uint2*)&h;
            }
#pragma unroll
            for (int ch = 0; ch < CPH; ++ch) Bc[ch] = Bn[ch];
        }
    }

    __syncthreads();   // xsl/wcl dead -> reuse LDS as transpose buffer

    // ---- transpose: ot[o][px], px row-major in the 8x16 tile ----
    const float bcv = bc[o_lane];
#pragma unroll
    for (int r = 0; r < 16; ++r) {
        int p  = (r & 3) + 8 * (r >> 2) + 4 * g;       // wave-local pixel 0..31
        int px = (p >> 2) * TC + w * 4 + (p & 3);
        sm.ot[m][px] = acc[r] + bcv;
    }
    __syncthreads();

    // ---- stores: one 16-col row chunk (64B) per thread ----
    {
        const int oo  = tid >> 3;          // 0..31
        const int seg = tid & 7;           // tile row
        const int o   = oh * 32 + oo;
        const int ho  = row0 + seg;
        if (ho < HO) {
            const float* src = &sm.ot[oo][seg * TC];
            size_t base = ((size_t)(b * FOUT + o) * HO + ho) * WO + col0;
            const int nst = (col0 + TC <= WO) ? TC : (WO - col0);
            for (int c = 0; c < nst; ++c) out[base + c] = src[c];
        }
    }
}

extern "C" void kernel_launch(void* const* d_in, const int* in_sizes, int n_in,
                              void* d_out, int out_size, void* d_ws, size_t ws_size,
                              hipStream_t stream) {
    const float* x  = (const float*)d_in[0];
    const float* Wf = (const float*)d_in[1];
    const float* bf = (const float*)d_in[2];
    const float* Wc = (const float*)d_in[3];
    const float* bc = (const float*)d_in[4];
    float* out = (float*)d_out;
    unsigned short* ws = (unsigned short*)d_ws;

    hipLaunchKernelGGL(prepass, dim3(32), dim3(256), 0, stream, Wf, bf, ws);

    // 1024 blocks: 16 rx x (8 cy x 2 oh) x 4 b, XCD-group swizzled
    hipLaunchKernelGGL(conv_mfma, dim3(1024), dim3(256), 0, stream,
                       x, Wc, bc, ws, out);
}